// Round 1
// baseline (314.757 us; speedup 1.0000x reference)
//
#include <hip/hip_runtime.h>
#include <stdint.h>
#include <math.h>

#define ROWLEN 84
#define TIECAP 16384u

__device__ __forceinline__ uint32_t map_f(float f) {
    uint32_t u = __float_as_uint(f);
    return (u & 0x80000000u) ? ~u : (u | 0x80000000u);
}
__device__ __forceinline__ float unmap_f(uint32_t u) {
    uint32_t b = (u & 0x80000000u) ? (u & 0x7FFFFFFFu) : ~u;
    return __uint_as_float(b);
}

// Find bin b (from top) such that suffix_count(b+1..) < target <= suffix_count(b..).
// res[0] = bin, res[1] = count strictly above bin. Called by all threads of a 256-thread block.
__device__ void find_from_top(const uint32_t* __restrict__ hist, int nbins, uint32_t target,
                              uint32_t* s_csum, volatile uint32_t* s_res) {
    int tid = threadIdx.x;
    int chunks = nbins / 256;
    uint32_t part = 0;
    for (int i = 0; i < chunks; ++i) part += hist[tid * chunks + i];
    s_csum[tid] = part;
    __syncthreads();
    if (tid == 0) {
        uint32_t acc = 0;
        int c;
        for (c = 255; c > 0; --c) {
            uint32_t cs = s_csum[c];
            if (acc + cs >= target) break;
            acc += cs;
        }
        int b = (c + 1) * chunks - 1;
        for (;; --b) {
            uint32_t hb = hist[b];
            if (acc + hb >= target) break;
            acc += hb;
        }
        s_res[0] = (uint32_t)b;
        s_res[1] = acc;
    }
    __syncthreads();
}

// Pass 1: per-row max over 80 class logits -> sortable uint key; level-1 histogram (top 11 bits).
__global__ void k_score_hist(const float* __restrict__ pred, uint32_t* __restrict__ scores,
                             uint32_t* __restrict__ gH1, int n) {
    __shared__ uint32_t h[2048];
    for (int i = threadIdx.x; i < 2048; i += blockDim.x) h[i] = 0;
    __syncthreads();
    int stride = gridDim.x * blockDim.x;
    for (int r = blockIdx.x * blockDim.x + threadIdx.x; r < n; r += stride) {
        const float4* p = (const float4*)(pred + (size_t)r * ROWLEN + 4);
        float m = -INFINITY;
#pragma unroll
        for (int j = 0; j < 20; ++j) {
            float4 v = p[j];
            m = fmaxf(m, fmaxf(fmaxf(v.x, v.y), fmaxf(v.z, v.w)));
        }
        uint32_t u = map_f(m);
        scores[r] = u;
        atomicAdd(&h[u >> 21], 1u);
    }
    __syncthreads();
    for (int i = threadIdx.x; i < 2048; i += blockDim.x)
        if (h[i]) atomicAdd(&gH1[i], h[i]);
}

// Pass 2: level-2 histogram (bits [20:10]) of keys whose top 11 bits == bin1.
__global__ void k_hist2(const uint32_t* __restrict__ scores, const uint32_t* __restrict__ gH1,
                        uint32_t* __restrict__ gH2, int n, uint32_t K) {
    __shared__ uint32_t h[2048];
    __shared__ uint32_t csum[256];
    __shared__ uint32_t res[2];
    for (int i = threadIdx.x; i < 2048; i += blockDim.x) h[i] = 0;
    find_from_top(gH1, 2048, K, csum, res);
    uint32_t bin1 = res[0];
    int stride = gridDim.x * blockDim.x;
    for (int r = blockIdx.x * blockDim.x + threadIdx.x; r < n; r += stride) {
        uint32_t u = scores[r];
        if ((u >> 21) == bin1) atomicAdd(&h[(u >> 10) & 0x7FFu], 1u);
    }
    __syncthreads();
    for (int i = threadIdx.x; i < 2048; i += blockDim.x)
        if (h[i]) atomicAdd(&gH2[i], h[i]);
}

// Pass 3: level-3 histogram (bits [9:0]) of keys whose top 22 bits == (bin1<<11)|bin2.
__global__ void k_hist3(const uint32_t* __restrict__ scores, const uint32_t* __restrict__ gH1,
                        const uint32_t* __restrict__ gH2, uint32_t* __restrict__ gH3,
                        int n, uint32_t K) {
    __shared__ uint32_t h[1024];
    __shared__ uint32_t csum[256];
    __shared__ uint32_t res[2];
    for (int i = threadIdx.x; i < 1024; i += blockDim.x) h[i] = 0;
    find_from_top(gH1, 2048, K, csum, res);
    uint32_t bin1 = res[0], chi1 = res[1];
    find_from_top(gH2, 2048, K - chi1, csum, res);
    uint32_t bin2 = res[0];
    uint32_t pref = (bin1 << 11) | bin2;
    int stride = gridDim.x * blockDim.x;
    for (int r = blockIdx.x * blockDim.x + threadIdx.x; r < n; r += stride) {
        uint32_t u = scores[r];
        if ((u >> 10) == pref) atomicAdd(&h[u & 0x3FFu], 1u);
    }
    __syncthreads();
    for (int i = threadIdx.x; i < 1024; i += blockDim.x)
        if (h[i]) atomicAdd(&gH3[i], h[i]);
}

// Pass 4: selection sum. Strictly-greater-than-threshold rows contribute score + box sum.
// Rows exactly equal to the k-th value are recorded for tie resolution.
__global__ void k_select(const float* __restrict__ pred, const uint32_t* __restrict__ scores,
                         const uint32_t* __restrict__ gH1, const uint32_t* __restrict__ gH2,
                         const uint32_t* __restrict__ gH3,
                         uint32_t* __restrict__ tieCnt, uint32_t* __restrict__ tieBuf,
                         float* __restrict__ out, int n, uint32_t K) {
    __shared__ uint32_t csum[256];
    __shared__ uint32_t res[2];
    __shared__ float wsum[4];
    find_from_top(gH1, 2048, K, csum, res);
    uint32_t bin1 = res[0], chi1 = res[1];
    find_from_top(gH2, 2048, K - chi1, csum, res);
    uint32_t bin2 = res[0], chi2 = res[1];
    find_from_top(gH3, 1024, K - chi1 - chi2, csum, res);
    uint32_t bin3 = res[0];
    uint32_t t_u = (bin1 << 21) | (bin2 << 10) | bin3;
    const uint32_t u_conf = 0xBE800000u;  // map_f(0.25f)
    bool tcut = (t_u >= u_conf);
    float lsum = 0.f;
    int stride = gridDim.x * blockDim.x;
    for (int r = blockIdx.x * blockDim.x + threadIdx.x; r < n; r += stride) {
        uint32_t u = scores[r];
        bool sel = tcut ? (u > t_u) : (u >= u_conf);
        if (sel) {
            float4 b = *(const float4*)(pred + (size_t)r * ROWLEN);
            lsum += unmap_f(u) + b.x + b.y + b.z + b.w;
        }
        if (tcut && u == t_u) {
            uint32_t pos = atomicAdd(tieCnt, 1u);
            if (pos < TIECAP) tieBuf[pos] = (uint32_t)r;
        }
    }
    for (int off = 32; off; off >>= 1) lsum += __shfl_down(lsum, off);
    int wid = threadIdx.x >> 6, lane = threadIdx.x & 63;
    if (lane == 0) wsum[wid] = lsum;
    __syncthreads();
    if (threadIdx.x == 0) atomicAdd(out, wsum[0] + wsum[1] + wsum[2] + wsum[3]);
}

// Pass 5: resolve ties at the k-th value: include the (K - count_gt) lowest-index tied rows.
__global__ void k_ties(const float* __restrict__ pred,
                       const uint32_t* __restrict__ gH1, const uint32_t* __restrict__ gH2,
                       const uint32_t* __restrict__ gH3,
                       const uint32_t* __restrict__ tieCnt, const uint32_t* __restrict__ tieBuf,
                       float* __restrict__ out, uint32_t K) {
    __shared__ uint32_t csum[256];
    __shared__ uint32_t res[2];
    __shared__ float wsum[4];
    find_from_top(gH1, 2048, K, csum, res);
    uint32_t bin1 = res[0], chi1 = res[1];
    find_from_top(gH2, 2048, K - chi1, csum, res);
    uint32_t bin2 = res[0], chi2 = res[1];
    find_from_top(gH3, 1024, K - chi1 - chi2, csum, res);
    uint32_t bin3 = res[0], chi3 = res[1];
    uint32_t t_u = (bin1 << 21) | (bin2 << 10) | bin3;
    const uint32_t u_conf = 0xBE800000u;
    if (t_u < u_conf) return;  // selection was score >= CONF; fully handled in k_select
    uint32_t C_gt = chi1 + chi2 + chi3;
    uint32_t m = K - C_gt;  // number of tied rows to include (>=1)
    uint32_t cnt = *tieCnt;
    if (cnt > TIECAP) cnt = TIECAP;
    float lsum = 0.f;
    if (m >= cnt) {
        for (uint32_t i = threadIdx.x; i < cnt; i += blockDim.x) {
            uint32_t r = tieBuf[i];
            float4 b = *(const float4*)(pred + (size_t)r * ROWLEN);
            lsum += b.x + b.y + b.z + b.w;
        }
    } else {
        for (uint32_t i = threadIdx.x; i < cnt; i += blockDim.x) {
            uint32_t ri = tieBuf[i];
            uint32_t rank = 0;
            for (uint32_t j = 0; j < cnt; ++j) rank += (tieBuf[j] < ri) ? 1u : 0u;
            if (rank < m) {
                float4 b = *(const float4*)(pred + (size_t)ri * ROWLEN);
                lsum += b.x + b.y + b.z + b.w;
            }
        }
    }
    for (int off = 32; off; off >>= 1) lsum += __shfl_down(lsum, off);
    int wid = threadIdx.x >> 6, lane = threadIdx.x & 63;
    if (lane == 0) wsum[wid] = lsum;
    __syncthreads();
    if (threadIdx.x == 0) atomicAdd(out, wsum[0] + wsum[1] + wsum[2] + wsum[3] + (float)m * unmap_f(t_u));
}

extern "C" void kernel_launch(void* const* d_in, const int* in_sizes, int n_in,
                              void* d_out, int out_size, void* d_ws, size_t ws_size,
                              hipStream_t stream) {
    const float* pred = (const float*)d_in[0];
    int n = in_sizes[0] / ROWLEN;
    double kd = ceil((double)n * 0.1);
    long kk = (long)kd;
    if (kk < 1) kk = 1;
    if (kk > n) kk = n;
    uint32_t K = (uint32_t)kk;

    uint32_t* ws32 = (uint32_t*)d_ws;
    uint32_t* scores = ws32;                // n words
    uint32_t* gH1 = ws32 + n;               // 2048
    uint32_t* gH2 = gH1 + 2048;             // 2048
    uint32_t* gH3 = gH2 + 2048;             // 1024
    uint32_t* tieCnt = gH3 + 1024;          // 16 (1 used)
    uint32_t* tieBuf = tieCnt + 16;         // TIECAP words

    hipMemsetAsync(d_out, 0, sizeof(float), stream);
    hipMemsetAsync(gH1, 0, (2048 + 2048 + 1024 + 16) * sizeof(uint32_t), stream);

    k_score_hist<<<2048, 256, 0, stream>>>(pred, scores, gH1, n);
    k_hist2<<<512, 256, 0, stream>>>(scores, gH1, gH2, n, K);
    k_hist3<<<512, 256, 0, stream>>>(scores, gH1, gH2, gH3, n, K);
    k_select<<<1024, 256, 0, stream>>>(pred, scores, gH1, gH2, gH3, tieCnt, tieBuf,
                                       (float*)d_out, n, K);
    k_ties<<<1, 256, 0, stream>>>(pred, gH1, gH2, gH3, tieCnt, tieBuf, (float*)d_out, K);
}

// Round 2
// 259.496 us; speedup vs baseline: 1.2130x; 1.2130x over previous
//
#include <hip/hip_runtime.h>
#include <stdint.h>
#include <math.h>

#define ROWLEN 84
#define F4PR 21            // float4s per row (84 floats)
#define RPB 256            // rows per tile
#define F4PT (RPB * F4PR)  // 5376 float4s per tile
#define TIECAP 16384u

__device__ __forceinline__ uint32_t map_f(float f) {
    uint32_t u = __float_as_uint(f);
    return (u & 0x80000000u) ? ~u : (u | 0x80000000u);
}
__device__ __forceinline__ float unmap_f(uint32_t u) {
    uint32_t b = (u & 0x80000000u) ? (u & 0x7FFFFFFFu) : ~u;
    return __uint_as_float(b);
}

// Find bin b (from top) such that suffix_count(b+1..) < target <= suffix_count(b..).
// res[0] = bin, res[1] = count strictly above bin. Called by all threads of a 256-thread block.
__device__ void find_from_top(const uint32_t* __restrict__ hist, int nbins, uint32_t target,
                              uint32_t* s_csum, volatile uint32_t* s_res) {
    int tid = threadIdx.x;
    int chunks = nbins / 256;
    uint32_t part = 0;
    for (int i = 0; i < chunks; ++i) part += hist[tid * chunks + i];
    s_csum[tid] = part;
    __syncthreads();
    if (tid == 0) {
        uint32_t acc = 0;
        int c;
        for (c = 255; c > 0; --c) {
            uint32_t cs = s_csum[c];
            if (acc + cs >= target) break;
            acc += cs;
        }
        int b = (c + 1) * chunks - 1;
        for (;; --b) {
            uint32_t hb = hist[b];
            if (acc + hb >= target) break;
            acc += hb;
        }
        s_res[0] = (uint32_t)b;
        s_res[1] = acc;
    }
    __syncthreads();
}

// Pass 1 (coalesced): stage 256-row tiles through LDS.
// Phase A: 21 contiguous 256-wide float4 loads -> per-float4 max -> pm[] (stride-1 store).
// Phase B: thread t reduces pm[21*t+1 .. 21*t+20] (stride-21 = 2 lanes/bank, free),
//          writes sortable key, LDS histogram of top 11 bits.
__global__ __launch_bounds__(256) void k_score_hist(const float* __restrict__ pred,
                                                    uint32_t* __restrict__ scores,
                                                    uint32_t* __restrict__ gH1, int n) {
    __shared__ float pm[F4PT];
    __shared__ uint32_t h[2048];
    for (int i = threadIdx.x; i < 2048; i += 256) h[i] = 0;
    const float4* pf4 = (const float4*)pred;
    size_t total_f4 = (size_t)n * F4PR;
    int ntiles = (n + RPB - 1) / RPB;
    for (int tile = blockIdx.x; tile < ntiles; tile += gridDim.x) {
        size_t base = (size_t)tile * F4PT;
        __syncthreads();  // pm reuse guard (also covers hist init on first tile)
#pragma unroll
        for (int it = 0; it < F4PR; ++it) {
            int l = it * 256 + threadIdx.x;
            size_t g = base + l;
            float m = -INFINITY;
            if (g < total_f4 && (l % F4PR) != 0) {  // component 0 = boxes, excluded
                float4 v = pf4[g];
                m = fmaxf(fmaxf(v.x, v.y), fmaxf(v.z, v.w));
            }
            pm[l] = m;
        }
        __syncthreads();
        int row = tile * RPB + threadIdx.x;
        if (row < n) {
            const float* q = pm + threadIdx.x * F4PR;
            float m = q[1];
#pragma unroll
            for (int j = 2; j <= 20; ++j) m = fmaxf(m, q[j]);
            uint32_t u = map_f(m);
            scores[row] = u;
            atomicAdd(&h[u >> 21], 1u);
        }
    }
    __syncthreads();
    for (int i = threadIdx.x; i < 2048; i += 256)
        if (h[i]) atomicAdd(&gH1[i], h[i]);
}

// Pass 2: level-2 histogram (bits [20:10]) of keys whose top 11 bits == bin1.
__global__ void k_hist2(const uint32_t* __restrict__ scores, const uint32_t* __restrict__ gH1,
                        uint32_t* __restrict__ gH2, int n, uint32_t K) {
    __shared__ uint32_t h[2048];
    __shared__ uint32_t csum[256];
    __shared__ uint32_t res[2];
    for (int i = threadIdx.x; i < 2048; i += blockDim.x) h[i] = 0;
    find_from_top(gH1, 2048, K, csum, res);
    uint32_t bin1 = res[0];
    int stride = gridDim.x * blockDim.x;
    for (int r = blockIdx.x * blockDim.x + threadIdx.x; r < n; r += stride) {
        uint32_t u = scores[r];
        if ((u >> 21) == bin1) atomicAdd(&h[(u >> 10) & 0x7FFu], 1u);
    }
    __syncthreads();
    for (int i = threadIdx.x; i < 2048; i += blockDim.x)
        if (h[i]) atomicAdd(&gH2[i], h[i]);
}

// Pass 3: level-3 histogram (bits [9:0]) of keys whose top 22 bits == (bin1<<11)|bin2.
__global__ void k_hist3(const uint32_t* __restrict__ scores, const uint32_t* __restrict__ gH1,
                        const uint32_t* __restrict__ gH2, uint32_t* __restrict__ gH3,
                        int n, uint32_t K) {
    __shared__ uint32_t h[1024];
    __shared__ uint32_t csum[256];
    __shared__ uint32_t res[2];
    for (int i = threadIdx.x; i < 1024; i += blockDim.x) h[i] = 0;
    find_from_top(gH1, 2048, K, csum, res);
    uint32_t bin1 = res[0], chi1 = res[1];
    find_from_top(gH2, 2048, K - chi1, csum, res);
    uint32_t bin2 = res[0];
    uint32_t pref = (bin1 << 11) | bin2;
    int stride = gridDim.x * blockDim.x;
    for (int r = blockIdx.x * blockDim.x + threadIdx.x; r < n; r += stride) {
        uint32_t u = scores[r];
        if ((u >> 10) == pref) atomicAdd(&h[u & 0x3FFu], 1u);
    }
    __syncthreads();
    for (int i = threadIdx.x; i < 1024; i += blockDim.x)
        if (h[i]) atomicAdd(&gH3[i], h[i]);
}

// Pass 4: selection sum. Strictly-greater-than-threshold rows contribute score + box sum.
// Rows exactly equal to the k-th value are recorded for tie resolution.
__global__ void k_select(const float* __restrict__ pred, const uint32_t* __restrict__ scores,
                         const uint32_t* __restrict__ gH1, const uint32_t* __restrict__ gH2,
                         const uint32_t* __restrict__ gH3,
                         uint32_t* __restrict__ tieCnt, uint32_t* __restrict__ tieBuf,
                         float* __restrict__ out, int n, uint32_t K) {
    __shared__ uint32_t csum[256];
    __shared__ uint32_t res[2];
    __shared__ float wsum[4];
    find_from_top(gH1, 2048, K, csum, res);
    uint32_t bin1 = res[0], chi1 = res[1];
    find_from_top(gH2, 2048, K - chi1, csum, res);
    uint32_t bin2 = res[0], chi2 = res[1];
    find_from_top(gH3, 1024, K - chi1 - chi2, csum, res);
    uint32_t bin3 = res[0];
    uint32_t t_u = (bin1 << 21) | (bin2 << 10) | bin3;
    const uint32_t u_conf = 0xBE800000u;  // map_f(0.25f)
    bool tcut = (t_u >= u_conf);
    float lsum = 0.f;
    int stride = gridDim.x * blockDim.x;
    for (int r = blockIdx.x * blockDim.x + threadIdx.x; r < n; r += stride) {
        uint32_t u = scores[r];
        bool sel = tcut ? (u > t_u) : (u >= u_conf);
        if (sel) {
            float4 b = *(const float4*)(pred + (size_t)r * ROWLEN);
            lsum += unmap_f(u) + b.x + b.y + b.z + b.w;
        }
        if (tcut && u == t_u) {
            uint32_t pos = atomicAdd(tieCnt, 1u);
            if (pos < TIECAP) tieBuf[pos] = (uint32_t)r;
        }
    }
    for (int off = 32; off; off >>= 1) lsum += __shfl_down(lsum, off);
    int wid = threadIdx.x >> 6, lane = threadIdx.x & 63;
    if (lane == 0) wsum[wid] = lsum;
    __syncthreads();
    if (threadIdx.x == 0) atomicAdd(out, wsum[0] + wsum[1] + wsum[2] + wsum[3]);
}

// Pass 5: resolve ties at the k-th value: include the (K - count_gt) lowest-index tied rows.
__global__ void k_ties(const float* __restrict__ pred,
                       const uint32_t* __restrict__ gH1, const uint32_t* __restrict__ gH2,
                       const uint32_t* __restrict__ gH3,
                       const uint32_t* __restrict__ tieCnt, const uint32_t* __restrict__ tieBuf,
                       float* __restrict__ out, uint32_t K) {
    __shared__ uint32_t csum[256];
    __shared__ uint32_t res[2];
    __shared__ float wsum[4];
    find_from_top(gH1, 2048, K, csum, res);
    uint32_t bin1 = res[0], chi1 = res[1];
    find_from_top(gH2, 2048, K - chi1, csum, res);
    uint32_t bin2 = res[0], chi2 = res[1];
    find_from_top(gH3, 1024, K - chi1 - chi2, csum, res);
    uint32_t bin3 = res[0], chi3 = res[1];
    uint32_t t_u = (bin1 << 21) | (bin2 << 10) | bin3;
    const uint32_t u_conf = 0xBE800000u;
    if (t_u < u_conf) return;  // selection was score >= CONF; fully handled in k_select
    uint32_t C_gt = chi1 + chi2 + chi3;
    uint32_t m = K - C_gt;  // number of tied rows to include (>=1)
    uint32_t cnt = *tieCnt;
    if (cnt > TIECAP) cnt = TIECAP;
    float lsum = 0.f;
    if (m >= cnt) {
        for (uint32_t i = threadIdx.x; i < cnt; i += blockDim.x) {
            uint32_t r = tieBuf[i];
            float4 b = *(const float4*)(pred + (size_t)r * ROWLEN);
            lsum += b.x + b.y + b.z + b.w;
        }
    } else {
        for (uint32_t i = threadIdx.x; i < cnt; i += blockDim.x) {
            uint32_t ri = tieBuf[i];
            uint32_t rank = 0;
            for (uint32_t j = 0; j < cnt; ++j) rank += (tieBuf[j] < ri) ? 1u : 0u;
            if (rank < m) {
                float4 b = *(const float4*)(pred + (size_t)ri * ROWLEN);
                lsum += b.x + b.y + b.z + b.w;
            }
        }
    }
    for (int off = 32; off; off >>= 1) lsum += __shfl_down(lsum, off);
    int wid = threadIdx.x >> 6, lane = threadIdx.x & 63;
    if (lane == 0) wsum[wid] = lsum;
    __syncthreads();
    if (threadIdx.x == 0) atomicAdd(out, wsum[0] + wsum[1] + wsum[2] + wsum[3] + (float)m * unmap_f(t_u));
}

extern "C" void kernel_launch(void* const* d_in, const int* in_sizes, int n_in,
                              void* d_out, int out_size, void* d_ws, size_t ws_size,
                              hipStream_t stream) {
    const float* pred = (const float*)d_in[0];
    int n = in_sizes[0] / ROWLEN;
    double kd = ceil((double)n * 0.1);
    long kk = (long)kd;
    if (kk < 1) kk = 1;
    if (kk > n) kk = n;
    uint32_t K = (uint32_t)kk;

    uint32_t* ws32 = (uint32_t*)d_ws;
    uint32_t* scores = ws32;                // n words
    uint32_t* gH1 = ws32 + n;               // 2048
    uint32_t* gH2 = gH1 + 2048;             // 2048
    uint32_t* gH3 = gH2 + 2048;             // 1024
    uint32_t* tieCnt = gH3 + 1024;          // 16 (1 used)
    uint32_t* tieBuf = tieCnt + 16;         // TIECAP words

    hipMemsetAsync(d_out, 0, sizeof(float), stream);
    hipMemsetAsync(gH1, 0, (2048 + 2048 + 1024 + 16) * sizeof(uint32_t), stream);

    k_score_hist<<<2048, 256, 0, stream>>>(pred, scores, gH1, n);
    k_hist2<<<512, 256, 0, stream>>>(scores, gH1, gH2, n, K);
    k_hist3<<<512, 256, 0, stream>>>(scores, gH1, gH2, gH3, n, K);
    k_select<<<1024, 256, 0, stream>>>(pred, scores, gH1, gH2, gH3, tieCnt, tieBuf,
                                       (float*)d_out, n, K);
    k_ties<<<1, 256, 0, stream>>>(pred, gH1, gH2, gH3, tieCnt, tieBuf, (float*)d_out, K);
}

// Round 3
// 236.148 us; speedup vs baseline: 1.3329x; 1.0989x over previous
//
#include <hip/hip_runtime.h>
#include <stdint.h>
#include <math.h>

#define ROWLEN 84
#define F4PR 21            // float4s per row (84 floats)
#define RPB 256            // rows per tile
#define F4PT (RPB * F4PR)  // 5376 float4s per tile
#define TIECAP 16384u

__device__ __forceinline__ uint32_t map_f(float f) {
    uint32_t u = __float_as_uint(f);
    return (u & 0x80000000u) ? ~u : (u | 0x80000000u);
}
__device__ __forceinline__ float unmap_f(uint32_t u) {
    uint32_t b = (u & 0x80000000u) ? (u & 0x7FFFFFFFu) : ~u;
    return __uint_as_float(b);
}

// Parallel top-down bin find: bin b such that suffix_count(b+1..) < target <= suffix_count(b..).
// 256 threads, single block. outBin / outAbove written by all threads' view via LDS.
__device__ void find_parallel(const uint32_t* __restrict__ hist, int nbins, uint32_t target,
                              uint32_t* s, uint32_t* sc2, uint32_t* outBin, uint32_t* outAbove) {
    int tid = threadIdx.x;
    int chunks = nbins / 256;
    int base = tid * chunks;
    uint32_t part = 0;
    for (int i = 0; i < chunks; ++i) part += hist[base + i];
    s[tid] = part;
    __syncthreads();
    // suffix sums: s[t] = sum_{t' >= t} part[t']
    for (int off = 1; off < 256; off <<= 1) {
        uint32_t v = (tid + off < 256) ? s[tid + off] : 0u;
        __syncthreads();
        s[tid] += v;
        __syncthreads();
    }
    uint32_t above_next = (tid < 255) ? s[tid + 1] : 0u;
    bool mine = (s[tid] >= target) && (above_next < target);  // exactly one thread
    if (mine) { sc2[0] = (uint32_t)tid; sc2[1] = above_next; }
    __syncthreads();
    uint32_t c = sc2[0], above = sc2[1];
    if (tid == 0) {  // <= 8 serial global reads within the chunk
        uint32_t acc = above;
        int b = (int)c * chunks + chunks - 1;
        for (;; --b) {
            uint32_t hb = hist[b];
            if (acc + hb >= target) break;
            acc += hb;
        }
        sc2[0] = (uint32_t)b;
        sc2[1] = acc;
    }
    __syncthreads();
    *outBin = sc2[0];
    *outAbove = sc2[1];
}

// Pass 1: ticket-scheduled 256-row tiles staged through LDS.
// Phase A: 21 coalesced 256-wide float4 loads -> per-float4 max -> pm[] (box lanes masked).
// Phase B: thread t reduces pm[21t+1 .. 21t+20] (2 lanes/bank = free), key + 1024-bin LDS hist.
__global__ __launch_bounds__(256) void k_score_hist(const float* __restrict__ pred,
                                                    uint32_t* __restrict__ scores,
                                                    uint32_t* __restrict__ gH1,
                                                    uint32_t* __restrict__ ticket, int n) {
    __shared__ float pm[F4PT];
    __shared__ uint32_t h[1024];
    __shared__ int s_tile;
    int tid = threadIdx.x;
    for (int i = tid; i < 1024; i += 256) h[i] = 0;
    uint32_t tid21 = (uint32_t)tid % 21u;
    const float4* pf4 = (const float4*)pred;
    size_t total_f4 = (size_t)n * F4PR;
    int ntiles = (n + RPB - 1) / RPB;
    for (;;) {
        __syncthreads();  // pm/s_tile reuse guard (also covers h init on first pass)
        if (tid == 0) s_tile = (int)atomicAdd(ticket, 1u);
        __syncthreads();
        int tile = s_tile;
        if (tile >= ntiles) break;
        size_t gbase = (size_t)tile * F4PT;
        int row0 = tile * RPB;
        if (row0 + RPB <= n) {
#pragma unroll
            for (int it = 0; it < F4PR; ++it) {
                const uint32_t BP = (21u - (4u * (uint32_t)it) % 21u) % 21u;  // box lane for this it
                float4 v = pf4[gbase + it * 256 + tid];
                float m = fmaxf(fmaxf(v.x, v.y), fmaxf(v.z, v.w));
                pm[it * 256 + tid] = (tid21 == BP) ? -INFINITY : m;
            }
        } else {
#pragma unroll
            for (int it = 0; it < F4PR; ++it) {
                const uint32_t BP = (21u - (4u * (uint32_t)it) % 21u) % 21u;
                int l = it * 256 + tid;
                size_t g = gbase + l;
                float m = -INFINITY;
                if (g < total_f4 && tid21 != BP) {
                    float4 v = pf4[g];
                    m = fmaxf(fmaxf(v.x, v.y), fmaxf(v.z, v.w));
                }
                pm[l] = m;
            }
        }
        __syncthreads();
        int row = row0 + tid;
        if (row < n) {
            const float* q = pm + tid * F4PR;
            float m = q[1];
#pragma unroll
            for (int j = 2; j <= 20; ++j) m = fmaxf(m, q[j]);
            uint32_t u = map_f(m);
            scores[row] = u;
            atomicAdd(&h[u >> 22], 1u);
        }
    }
    __syncthreads();
    for (int i = tid; i < 1024; i += 256)
        if (h[i]) atomicAdd(&gH1[i], h[i]);
}

// Level-1 select (1 block): bin1/chi1 from gH1 (1024 bins, bits [31:22]).
__global__ void k_sel1(const uint32_t* __restrict__ gH1, uint32_t* __restrict__ sres, uint32_t K) {
    __shared__ uint32_t s[256];
    __shared__ uint32_t sc2[2];
    uint32_t bin, above;
    find_parallel(gH1, 1024, K, s, sc2, &bin, &above);
    if (threadIdx.x == 0) { sres[0] = bin; sres[1] = above; }
}

// Level-2 histogram: bits [21:11] of keys whose top 10 bits == bin1.
__global__ void k_hist2(const uint32_t* __restrict__ scores, const uint32_t* __restrict__ sres,
                        uint32_t* __restrict__ gH2, int n) {
    __shared__ uint32_t h[2048];
    for (int i = threadIdx.x; i < 2048; i += blockDim.x) h[i] = 0;
    __syncthreads();
    uint32_t bin1 = sres[0];
    int stride = gridDim.x * blockDim.x;
    for (int r = blockIdx.x * blockDim.x + threadIdx.x; r < n; r += stride) {
        uint32_t u = scores[r];
        if ((u >> 22) == bin1) atomicAdd(&h[(u >> 11) & 0x7FFu], 1u);
    }
    __syncthreads();
    for (int i = threadIdx.x; i < 2048; i += blockDim.x)
        if (h[i]) atomicAdd(&gH2[i], h[i]);
}

// Level-2 select (1 block).
__global__ void k_sel2(const uint32_t* __restrict__ gH2, uint32_t* __restrict__ sres, uint32_t K) {
    __shared__ uint32_t s[256];
    __shared__ uint32_t sc2[2];
    uint32_t chi1 = sres[1];
    uint32_t bin, above;
    find_parallel(gH2, 2048, K - chi1, s, sc2, &bin, &above);
    if (threadIdx.x == 0) { sres[2] = bin; sres[3] = above; }
}

// Level-3 histogram: bits [10:0] of keys whose top 21 bits == (bin1<<11)|bin2.
__global__ void k_hist3(const uint32_t* __restrict__ scores, const uint32_t* __restrict__ sres,
                        uint32_t* __restrict__ gH3, int n) {
    __shared__ uint32_t h[2048];
    for (int i = threadIdx.x; i < 2048; i += blockDim.x) h[i] = 0;
    __syncthreads();
    uint32_t pref = (sres[0] << 11) | sres[2];
    int stride = gridDim.x * blockDim.x;
    for (int r = blockIdx.x * blockDim.x + threadIdx.x; r < n; r += stride) {
        uint32_t u = scores[r];
        if ((u >> 11) == pref) atomicAdd(&h[u & 0x7FFu], 1u);
    }
    __syncthreads();
    for (int i = threadIdx.x; i < 2048; i += blockDim.x)
        if (h[i]) atomicAdd(&gH3[i], h[i]);
}

// Level-3 select (1 block): final threshold t_u, tie count m.
__global__ void k_sel3(const uint32_t* __restrict__ gH3, uint32_t* __restrict__ sres, uint32_t K) {
    __shared__ uint32_t s[256];
    __shared__ uint32_t sc2[2];
    uint32_t chi1 = sres[1], chi2 = sres[3];
    uint32_t bin, above;
    find_parallel(gH3, 2048, K - chi1 - chi2, s, sc2, &bin, &above);
    if (threadIdx.x == 0) {
        uint32_t t_u = (sres[0] << 22) | (sres[2] << 11) | bin;
        uint32_t C_gt = chi1 + chi2 + above;
        sres[4] = bin;
        sres[5] = above;
        sres[6] = t_u;
        sres[7] = K - C_gt;  // m >= 1 tied rows to include
    }
}

// Pass 4: selection sum. Strictly-greater rows contribute score + box sum; ties recorded.
__global__ void k_select(const float* __restrict__ pred, const uint32_t* __restrict__ scores,
                         const uint32_t* __restrict__ sres,
                         uint32_t* __restrict__ tieCnt, uint32_t* __restrict__ tieBuf,
                         float* __restrict__ out, int n) {
    __shared__ float wsum[4];
    uint32_t t_u = sres[6];
    const uint32_t u_conf = 0xBE800000u;  // map_f(0.25f)
    bool tcut = (t_u >= u_conf);
    float lsum = 0.f;
    int stride = gridDim.x * blockDim.x;
    for (int r = blockIdx.x * blockDim.x + threadIdx.x; r < n; r += stride) {
        uint32_t u = scores[r];
        bool sel = tcut ? (u > t_u) : (u >= u_conf);
        if (sel) {
            float4 b = *(const float4*)(pred + (size_t)r * ROWLEN);
            lsum += unmap_f(u) + b.x + b.y + b.z + b.w;
        }
        if (tcut && u == t_u) {
            uint32_t pos = atomicAdd(tieCnt, 1u);
            if (pos < TIECAP) tieBuf[pos] = (uint32_t)r;
        }
    }
    for (int off = 32; off; off >>= 1) lsum += __shfl_down(lsum, off);
    int wid = threadIdx.x >> 6, lane = threadIdx.x & 63;
    if (lane == 0) wsum[wid] = lsum;
    __syncthreads();
    if (threadIdx.x == 0) atomicAdd(out, wsum[0] + wsum[1] + wsum[2] + wsum[3]);
}

// Pass 5: include the m lowest-index tied rows (boxes + m * t).
__global__ void k_ties(const float* __restrict__ pred, const uint32_t* __restrict__ sres,
                       const uint32_t* __restrict__ tieCnt, const uint32_t* __restrict__ tieBuf,
                       float* __restrict__ out) {
    __shared__ float wsum[4];
    uint32_t t_u = sres[6];
    const uint32_t u_conf = 0xBE800000u;
    if (t_u < u_conf) return;  // selection was score >= CONF; fully handled in k_select
    uint32_t m = sres[7];
    uint32_t cnt = *tieCnt;
    if (cnt > TIECAP) cnt = TIECAP;
    float lsum = 0.f;
    if (m >= cnt) {
        for (uint32_t i = threadIdx.x; i < cnt; i += blockDim.x) {
            uint32_t r = tieBuf[i];
            float4 b = *(const float4*)(pred + (size_t)r * ROWLEN);
            lsum += b.x + b.y + b.z + b.w;
        }
    } else {
        for (uint32_t i = threadIdx.x; i < cnt; i += blockDim.x) {
            uint32_t ri = tieBuf[i];
            uint32_t rank = 0;
            for (uint32_t j = 0; j < cnt; ++j) rank += (tieBuf[j] < ri) ? 1u : 0u;
            if (rank < m) {
                float4 b = *(const float4*)(pred + (size_t)ri * ROWLEN);
                lsum += b.x + b.y + b.z + b.w;
            }
        }
    }
    for (int off = 32; off; off >>= 1) lsum += __shfl_down(lsum, off);
    int wid = threadIdx.x >> 6, lane = threadIdx.x & 63;
    if (lane == 0) wsum[wid] = lsum;
    __syncthreads();
    if (threadIdx.x == 0)
        atomicAdd(out, wsum[0] + wsum[1] + wsum[2] + wsum[3] + (float)m * unmap_f(t_u));
}

extern "C" void kernel_launch(void* const* d_in, const int* in_sizes, int n_in,
                              void* d_out, int out_size, void* d_ws, size_t ws_size,
                              hipStream_t stream) {
    const float* pred = (const float*)d_in[0];
    int n = in_sizes[0] / ROWLEN;
    double kd = ceil((double)n * 0.1);
    long kk = (long)kd;
    if (kk < 1) kk = 1;
    if (kk > n) kk = n;
    uint32_t K = (uint32_t)kk;

    uint32_t* ws32 = (uint32_t*)d_ws;
    uint32_t* scores = ws32;                 // n words
    uint32_t* gH1 = ws32 + n;                // 1024
    uint32_t* gH2 = gH1 + 1024;              // 2048
    uint32_t* gH3 = gH2 + 2048;              // 2048
    uint32_t* sres = gH3 + 2048;             // 16
    uint32_t* tieCnt = sres + 16;            // 16 (1 used)
    uint32_t* ticket = tieCnt + 16;          // 16 (1 used)
    uint32_t* tieBuf = ticket + 16;          // TIECAP words

    hipMemsetAsync(d_out, 0, sizeof(float), stream);
    hipMemsetAsync(gH1, 0, (1024 + 2048 + 2048 + 16 + 16 + 16) * sizeof(uint32_t), stream);

    k_score_hist<<<2048, 256, 0, stream>>>(pred, scores, gH1, ticket, n);
    k_sel1<<<1, 256, 0, stream>>>(gH1, sres, K);
    k_hist2<<<1024, 256, 0, stream>>>(scores, sres, gH2, n);
    k_sel2<<<1, 256, 0, stream>>>(gH2, sres, K);
    k_hist3<<<1024, 256, 0, stream>>>(scores, sres, gH3, n);
    k_sel3<<<1, 256, 0, stream>>>(gH3, sres, K);
    k_select<<<2048, 256, 0, stream>>>(pred, scores, sres, tieCnt, tieBuf, (float*)d_out, n);
    k_ties<<<1, 256, 0, stream>>>(pred, sres, tieCnt, tieBuf, (float*)d_out);
}